// Round 1
// baseline (24.803 us; speedup 1.0000x reference)
//
#include <hip/hip_runtime.h>
#include <math.h>

#define WIDTH   1024
#define NROWS   8192        // N
#define NCOLS   8193        // N + 1 (bias in last column)
#define N_LAYERS 8

// One wave (64 lanes) computes one output row's dot product.
// Block = 256 threads = 4 waves = 4 rows; grid = 256 blocks -> 1024 rows.
__global__ __launch_bounds__(256) void mlp_layer_kernel(
    const float* __restrict__ P,     // parameter_matrix, row-major (8192 x 8193)
    const float* __restrict__ hin,   // input activation (1024)
    float* __restrict__ hout,        // output activation (1024)
    int l,                           // layer index 1..7
    int apply_silu)
{
    const int wave = threadIdx.x >> 6;
    const int lane = threadIdx.x & 63;
    const int row  = (blockIdx.x << 2) + wave;          // 0..1023

    const size_t rowbase = (size_t)(l * WIDTH + row) * (size_t)NCOLS;
    const float* __restrict__ wrow = P + rowbase + (size_t)(l - 1) * WIDTH;

    // 1024-element dot product: 16 coalesced dword loads per lane.
    // (row stride 8193 floats is odd -> rows are not 16B aligned; float4
    //  reinterpret would be UB, scalar dwords are still fully coalesced)
    float sum = 0.f;
    #pragma unroll
    for (int j = 0; j < 16; ++j) {
        const int idx = (j << 6) + lane;
        sum += wrow[idx] * hin[idx];
    }

    // wave64 butterfly reduce
    #pragma unroll
    for (int off = 32; off > 0; off >>= 1)
        sum += __shfl_xor(sum, off, 64);

    if (lane == 0) {
        float a = sum + P[rowbase + NROWS];              // + bias (col N)
        if (apply_silu) {
            a = a / (1.f + __expf(-a));                  // silu
        }
        hout[row] = a;
    }
}

extern "C" void kernel_launch(void* const* d_in, const int* in_sizes, int n_in,
                              void* d_out, int out_size, void* d_ws, size_t ws_size,
                              hipStream_t stream) {
    const float* x = (const float*)d_in[0];              // (1024,)
    const float* P = (const float*)d_in[1];              // (8192, 8193)
    float* out = (float*)d_out;                          // (1024,)

    float* h0 = (float*)d_ws;                            // ping
    float* h1 = h0 + WIDTH;                              // pong

    const float* cur = x;
    for (int l = 1; l < N_LAYERS; ++l) {
        const bool last = (l == N_LAYERS - 1);
        float* dst = last ? out : ((l & 1) ? h0 : h1);
        mlp_layer_kernel<<<dim3(256), dim3(256), 0, stream>>>(
            P, cur, dst, l, last ? 0 : 1);
        cur = dst;
    }
}